// Round 1
// baseline (164.891 us; speedup 1.0000x reference)
//
#include <hip/hip_runtime.h>
#include <hip/hip_bf16.h>

#define CDIM 4096
#define DDIM 1024
#define BDIM 16384

using frag_ab = __attribute__((ext_vector_type(8))) short;   // 8 bf16 (4 VGPRs)
using frag_cd = __attribute__((ext_vector_type(4))) float;   // 4 fp32

typedef __attribute__((address_space(1))) const void gvoid;
typedef __attribute__((address_space(3))) void lvoid;

__device__ __forceinline__ float block_sum(float v, float* red) {
  int t = threadIdx.x;
  #pragma unroll
  for (int off = 32; off; off >>= 1) v += __shfl_xor(v, off);
  __syncthreads();
  if ((t & 63) == 0) red[t >> 6] = v;
  __syncthreads();
  return (red[0] + red[1]) + (red[2] + red[3]);
}

// ---- Kernel A: wn = bf16( weight_row / max(||row||, 1e-8) ) ----
__global__ __launch_bounds__(256) void k_norm(const float* __restrict__ w,
                                              __hip_bfloat16* __restrict__ wnb) {
  __shared__ float red[4];
  __shared__ float s_inv;
  int row = blockIdx.x, t = threadIdx.x;
  const float4* wr = (const float4*)(w + (size_t)row * DDIM);
  float4 x = wr[t];                      // 1024 floats = 256 float4, 1 per thread
  float ss = (x.x * x.x + x.y * x.y) + (x.z * x.z + x.w * x.w);
  ss = block_sum(ss, red);
  if (t == 0) s_inv = 1.0f / fmaxf(sqrtf(ss), 1e-8f);
  __syncthreads();
  float inv = s_inv;
  __hip_bfloat16* o = wnb + (size_t)row * DDIM + t * 4;
  o[0] = __float2bfloat16(x.x * inv);
  o[1] = __float2bfloat16(x.y * inv);
  o[2] = __float2bfloat16(x.z * inv);
  o[3] = __float2bfloat16(x.w * inv);
}

// ---- Kernel B: e = exp(wn @ wn^T)  (128x128 tile, 4 waves, 16x16x32 bf16 MFMA) ----
__global__ __launch_bounds__(256) void k_simexp(const __hip_bfloat16* __restrict__ wb,
                                                float* __restrict__ e) {
  __shared__ __hip_bfloat16 As[128 * 32];
  __shared__ __hip_bfloat16 Bs[128 * 32];
  int tid = threadIdx.x;
  int bcol = blockIdx.x, brow = blockIdx.y;
  int lane = tid & 63, wid = tid >> 6;
  int wm = wid >> 1, wn2 = wid & 1;            // 2x2 waves, each 64x64 output
  frag_cd acc[4][4] = {};

  // staging: thread t covers 16B = 8 bf16; row = t/4, k-chunk = t%4
  int srow = tid >> 2;
  int selem = (tid & 3) * 8;
  const __hip_bfloat16* gA = wb + (size_t)(brow * 128 + srow) * DDIM + selem;
  const __hip_bfloat16* gB = wb + (size_t)(bcol * 128 + srow) * DDIM + selem;
  char* lA = (char*)As + tid * 16;
  char* lB = (char*)Bs + tid * 16;

  int lrow = lane & 15, lk = (lane >> 4) * 8;
  const __hip_bfloat16* pa0 = As + (wm * 64 + lrow) * 32 + lk;
  const __hip_bfloat16* pb0 = Bs + (wn2 * 64 + lrow) * 32 + lk;

  for (int k0 = 0; k0 < DDIM; k0 += 32) {
    __builtin_amdgcn_global_load_lds((gvoid*)(gA + k0),             (lvoid*)lA,          16, 0, 0);
    __builtin_amdgcn_global_load_lds((gvoid*)(gA + k0 + 64 * DDIM), (lvoid*)(lA + 4096), 16, 0, 0);
    __builtin_amdgcn_global_load_lds((gvoid*)(gB + k0),             (lvoid*)lB,          16, 0, 0);
    __builtin_amdgcn_global_load_lds((gvoid*)(gB + k0 + 64 * DDIM), (lvoid*)(lB + 4096), 16, 0, 0);
    __syncthreads();
    frag_ab a[4], b[4];
    #pragma unroll
    for (int m = 0; m < 4; m++) a[m] = *(const frag_ab*)(const void*)(pa0 + m * 16 * 32);
    #pragma unroll
    for (int n = 0; n < 4; n++) b[n] = *(const frag_ab*)(const void*)(pb0 + n * 16 * 32);
    #pragma unroll
    for (int m = 0; m < 4; m++)
      #pragma unroll
      for (int n = 0; n < 4; n++)
        acc[m][n] = __builtin_amdgcn_mfma_f32_16x16x32_bf16(a[m], b[n], acc[m][n], 0, 0, 0);
    __syncthreads();
  }

  // C/D layout (verified m89/m91): col = lane&15, row = (lane>>4)*4 + reg
  int r0 = brow * 128 + wm * 64;
  int c0 = bcol * 128 + wn2 * 64 + (lane & 15);
  int rg = (lane >> 4) * 4;
  #pragma unroll
  for (int m = 0; m < 4; m++)
    #pragma unroll
    for (int n = 0; n < 4; n++)
      #pragma unroll
      for (int j = 0; j < 4; j++) {
        int r = r0 + m * 16 + rg + j;
        int c = c0 + n * 16;
        e[(size_t)r * CDIM + c] = __expf(acc[m][n][j]);
      }
}

// ---- Kernel C: per-row stats of e ----
__global__ __launch_bounds__(256) void k_rowstats(const float* __restrict__ e,
                                                  float* __restrict__ Sf,
                                                  float* __restrict__ rv,
                                                  float* __restrict__ ed) {
  __shared__ float red[4];
  int r = blockIdx.x, t = threadIdx.x;
  const float4* er = (const float4*)(e + (size_t)r * CDIM);
  float s = 0.f;
  #pragma unroll
  for (int i = 0; i < 4; i++) {
    float4 v = er[t + i * 256];
    s += (v.x + v.y) + (v.z + v.w);
  }
  s = block_sum(s, red);
  if (t == 0) {
    float d = e[(size_t)r * CDIM + r];
    Sf[r] = s; ed[r] = d; rv[r] = 1.0f / (s - d);
  }
}

// ---- Kernel D: per-sample loss ----
__global__ __launch_bounds__(256) void k_loss(const float* __restrict__ pred,
                                              const int* __restrict__ tgt,
                                              const float* __restrict__ e,
                                              const float* __restrict__ Sf,
                                              const float* __restrict__ rv,
                                              const float* __restrict__ ed,
                                              float* __restrict__ part) {
  __shared__ float red[4];
  int i = blockIdx.x, t = threadIdx.x;
  const float4* pr = (const float4*)(pred + (size_t)i * CDIM);
  float4 loc[4];
  float mx = -3.4e38f;
  #pragma unroll
  for (int j = 0; j < 4; j++) {
    float4 v = pr[t + j * 256];
    loc[j] = v;
    mx = fmaxf(fmaxf(mx, fmaxf(v.x, v.y)), fmaxf(v.z, v.w));
  }
  #pragma unroll
  for (int off = 32; off; off >>= 1) mx = fmaxf(mx, __shfl_xor(mx, off));
  if ((t & 63) == 0) red[t >> 6] = mx;
  __syncthreads();
  mx = fmaxf(fmaxf(red[0], red[1]), fmaxf(red[2], red[3]));

  float se = 0.f;
  #pragma unroll
  for (int j = 0; j < 4; j++)
    se += (__expf(loc[j].x - mx) + __expf(loc[j].y - mx)) +
          (__expf(loc[j].z - mx) + __expf(loc[j].w - mx));
  se = block_sum(se, red);
  float lse = mx + __logf(se);

  int tg = tgt[i];
  const float4* er = (const float4*)(e + (size_t)tg * CDIM);
  float dot = 0.f;
  #pragma unroll
  for (int j = 0; j < 4; j++) {
    float4 ev = er[t + j * 256];
    dot += (ev.x * loc[j].x + ev.y * loc[j].y) + (ev.z * loc[j].z + ev.w * loc[j].w);
  }
  dot = block_sum(dot, red);

  if (t == 0) {
    float pt = pred[(size_t)i * CDIM + tg];
    float ce = lse - pt;
    // sum_{c != t} conf[t,c]*(lse - pred[c]) = rinv*(S*lse - dot - ed*(lse - pred[t]))
    float t2 = rv[tg] * (Sf[tg] * lse - dot - ed[tg] * ce);
    part[i] = 0.9f * ce + 0.1f * t2;
  }
}

// ---- Kernel E: deterministic final reduce ----
__global__ __launch_bounds__(256) void k_final(const float* __restrict__ part,
                                               float* __restrict__ out) {
  __shared__ float red[4];
  int t = threadIdx.x;
  float s = 0.f;
  for (int i = t; i < BDIM; i += 256) s += part[i];
  s = block_sum(s, red);
  if (t == 0) out[0] = s * (1.0f / BDIM);
}

extern "C" void kernel_launch(void* const* d_in, const int* in_sizes, int n_in,
                              void* d_out, int out_size, void* d_ws, size_t ws_size,
                              hipStream_t stream) {
  const float* pred = (const float*)d_in[0];
  const float* weight = (const float*)d_in[1];
  const int* target = (const int*)d_in[2];
  float* out = (float*)d_out;
  char* ws = (char*)d_ws;

  __hip_bfloat16* wnb = (__hip_bfloat16*)ws;                     // 8 MB
  float* e    = (float*)(ws + (size_t)(8u << 20));               // 64 MB
  float* Sf   = (float*)(ws + (size_t)(72u << 20));              // 16 KB
  float* rv   = (float*)(ws + (size_t)(72u << 20) + 16384);      // 16 KB
  float* ed   = (float*)(ws + (size_t)(72u << 20) + 32768);      // 16 KB
  float* part = (float*)(ws + (size_t)(72u << 20) + 49152);      // 64 KB

  k_norm<<<dim3(CDIM), dim3(256), 0, stream>>>(weight, wnb);
  k_simexp<<<dim3(32, 32), dim3(256), 0, stream>>>(wnb, e);
  k_rowstats<<<dim3(CDIM), dim3(256), 0, stream>>>(e, Sf, rv, ed);
  k_loss<<<dim3(BDIM), dim3(256), 0, stream>>>(pred, target, e, Sf, rv, ed, part);
  k_final<<<dim3(1), dim3(256), 0, stream>>>(part, out);
}

// Round 2
// 145.418 us; speedup vs baseline: 1.1339x; 1.1339x over previous
//
#include <hip/hip_runtime.h>
#include <hip/hip_bf16.h>

#define CDIM 4096
#define DDIM 1024
#define BDIM 16384
#define EDIAG 2.7182818284590452f

using frag_ab = __attribute__((ext_vector_type(8))) short;   // 8 bf16 (4 VGPRs)
using frag_cd = __attribute__((ext_vector_type(4))) float;   // 4 fp32

typedef __attribute__((address_space(1))) const void gvoid;
typedef __attribute__((address_space(3))) void lvoid;

__device__ __forceinline__ float block_sum(float v, float* red) {
  int t = threadIdx.x;
  #pragma unroll
  for (int off = 32; off; off >>= 1) v += __shfl_xor(v, off);
  __syncthreads();
  if ((t & 63) == 0) red[t >> 6] = v;
  __syncthreads();
  return (red[0] + red[1]) + (red[2] + red[3]);
}

__device__ __forceinline__ float bf2f(short s) {
  return __uint_as_float(((unsigned)(unsigned short)s) << 16);
}

// ---- Kernel A: wn = bf16( weight_row / max(||row||, 1e-8) ); also zero Sf ----
__global__ __launch_bounds__(256) void k_norm(const float* __restrict__ w,
                                              __hip_bfloat16* __restrict__ wnb,
                                              float* __restrict__ Sf) {
  __shared__ float red[4];
  __shared__ float s_inv;
  int row = blockIdx.x, t = threadIdx.x;
  const float4* wr = (const float4*)(w + (size_t)row * DDIM);
  float4 x = wr[t];                      // 1024 floats = 256 float4, 1 per thread
  float ss = (x.x * x.x + x.y * x.y) + (x.z * x.z + x.w * x.w);
  ss = block_sum(ss, red);
  if (t == 0) {
    s_inv = 1.0f / fmaxf(sqrtf(ss), 1e-8f);
    Sf[row] = 0.0f;                      // init for fused row-sum atomics
  }
  __syncthreads();
  float inv = s_inv;
  __hip_bfloat16* o = wnb + (size_t)row * DDIM + t * 4;
  o[0] = __float2bfloat16(x.x * inv);
  o[1] = __float2bfloat16(x.y * inv);
  o[2] = __float2bfloat16(x.z * inv);
  o[3] = __float2bfloat16(x.w * inv);
}

// ---- Kernel B: e = bf16(exp(wn @ wn^T)) + fused row sums ----
// 128x128 tile, 4 waves (2x2), 16x16x32 bf16 MFMA, global_load_lds width=16.
__global__ __launch_bounds__(256) void k_simexp(const __hip_bfloat16* __restrict__ wb,
                                                __hip_bfloat16* __restrict__ ebf,
                                                float* __restrict__ Sf) {
  __shared__ __hip_bfloat16 As[128 * 32];
  __shared__ __hip_bfloat16 Bs[128 * 32];
  int tid = threadIdx.x;
  int bcol = blockIdx.x, brow = blockIdx.y;
  int lane = tid & 63, wid = tid >> 6;
  int wm = wid >> 1, wn2 = wid & 1;            // 2x2 waves, each 64x64 output
  frag_cd acc[4][4] = {};

  // staging: thread t covers 16B = 8 bf16; row = t/4, k-chunk = t%4
  int srow = tid >> 2;
  int selem = (tid & 3) * 8;
  const __hip_bfloat16* gA = wb + (size_t)(brow * 128 + srow) * DDIM + selem;
  const __hip_bfloat16* gB = wb + (size_t)(bcol * 128 + srow) * DDIM + selem;
  char* lA = (char*)As + tid * 16;
  char* lB = (char*)Bs + tid * 16;

  int l15 = lane & 15, lk = (lane >> 4) * 8;
  const __hip_bfloat16* pa0 = As + (wm * 64 + l15) * 32 + lk;
  const __hip_bfloat16* pb0 = Bs + (wn2 * 64 + l15) * 32 + lk;

  for (int k0 = 0; k0 < DDIM; k0 += 32) {
    __builtin_amdgcn_global_load_lds((gvoid*)(gA + k0),             (lvoid*)lA,          16, 0, 0);
    __builtin_amdgcn_global_load_lds((gvoid*)(gA + k0 + 64 * DDIM), (lvoid*)(lA + 4096), 16, 0, 0);
    __builtin_amdgcn_global_load_lds((gvoid*)(gB + k0),             (lvoid*)lB,          16, 0, 0);
    __builtin_amdgcn_global_load_lds((gvoid*)(gB + k0 + 64 * DDIM), (lvoid*)(lB + 4096), 16, 0, 0);
    __syncthreads();
    frag_ab a[4], b[4];
    #pragma unroll
    for (int m = 0; m < 4; m++) a[m] = *(const frag_ab*)(const void*)(pa0 + m * 16 * 32);
    #pragma unroll
    for (int n = 0; n < 4; n++) b[n] = *(const frag_ab*)(const void*)(pb0 + n * 16 * 32);
    #pragma unroll
    for (int m = 0; m < 4; m++)
      #pragma unroll
      for (int n = 0; n < 4; n++)
        acc[m][n] = __builtin_amdgcn_mfma_f32_16x16x32_bf16(a[m], b[n], acc[m][n], 0, 0, 0);
    __syncthreads();
  }

  // C/D layout (verified m89/m91): col = lane&15, row = (lane>>4)*4 + reg
  int r0 = brow * 128 + wm * 64;
  int c0 = bcol * 128 + wn2 * 64 + l15;
  int rg = (lane >> 4) * 4;
  #pragma unroll
  for (int m = 0; m < 4; m++)
    #pragma unroll
    for (int j = 0; j < 4; j++) {
      int r = r0 + m * 16 + rg + j;
      float rsum = 0.f;
      #pragma unroll
      for (int n = 0; n < 4; n++) {
        float ex = __expf(acc[m][n][j]);
        ebf[(size_t)r * CDIM + c0 + n * 16] = __float2bfloat16(ex);
        rsum += ex;
      }
      // reduce across the 16 lanes (lane&15) sharing this row
      rsum += __shfl_xor(rsum, 1);
      rsum += __shfl_xor(rsum, 2);
      rsum += __shfl_xor(rsum, 4);
      rsum += __shfl_xor(rsum, 8);
      if (l15 == 0) atomicAdd(&Sf[r], rsum);
    }
}

// ---- Kernel C: per-sample loss ----
__global__ __launch_bounds__(256) void k_loss(const float* __restrict__ pred,
                                              const int* __restrict__ tgt,
                                              const __hip_bfloat16* __restrict__ ebf,
                                              const float* __restrict__ Sf,
                                              float* __restrict__ part) {
  __shared__ float red[4];
  int i = blockIdx.x, t = threadIdx.x;
  const float4* pr = (const float4*)(pred + (size_t)i * CDIM);
  float4 loc[4];
  float mx = -3.4e38f;
  #pragma unroll
  for (int j = 0; j < 4; j++) {
    float4 v = pr[t + j * 256];
    loc[j] = v;
    mx = fmaxf(fmaxf(mx, fmaxf(v.x, v.y)), fmaxf(v.z, v.w));
  }
  #pragma unroll
  for (int off = 32; off; off >>= 1) mx = fmaxf(mx, __shfl_xor(mx, off));
  if ((t & 63) == 0) red[t >> 6] = mx;
  __syncthreads();
  mx = fmaxf(fmaxf(red[0], red[1]), fmaxf(red[2], red[3]));

  float se = 0.f;
  #pragma unroll
  for (int j = 0; j < 4; j++)
    se += (__expf(loc[j].x - mx) + __expf(loc[j].y - mx)) +
          (__expf(loc[j].z - mx) + __expf(loc[j].w - mx));
  se = block_sum(se, red);
  float lse = mx + __logf(se);

  int tg = tgt[i];
  const short4* er = (const short4*)(ebf + (size_t)tg * CDIM);
  float dot = 0.f;
  #pragma unroll
  for (int j = 0; j < 4; j++) {
    short4 ev = er[t + j * 256];
    dot += (bf2f(ev.x) * loc[j].x + bf2f(ev.y) * loc[j].y) +
           (bf2f(ev.z) * loc[j].z + bf2f(ev.w) * loc[j].w);
  }
  dot = block_sum(dot, red);

  if (t == 0) {
    float pt = pred[(size_t)i * CDIM + tg];
    float ce = lse - pt;
    // sum_{c != t} conf[t,c]*(lse - pred[c]) = (S*lse - dot - e^1*ce) / (S - e^1)
    float S = Sf[tg];
    float t2 = (S * lse - dot - EDIAG * ce) / (S - EDIAG);
    part[i] = 0.9f * ce + 0.1f * t2;
  }
}

// ---- Kernel D: deterministic final reduce ----
__global__ __launch_bounds__(256) void k_final(const float* __restrict__ part,
                                               float* __restrict__ out) {
  __shared__ float red[4];
  int t = threadIdx.x;
  float s = 0.f;
  for (int i = t; i < BDIM; i += 256) s += part[i];
  s = block_sum(s, red);
  if (t == 0) out[0] = s * (1.0f / BDIM);
}

extern "C" void kernel_launch(void* const* d_in, const int* in_sizes, int n_in,
                              void* d_out, int out_size, void* d_ws, size_t ws_size,
                              hipStream_t stream) {
  const float* pred = (const float*)d_in[0];
  const float* weight = (const float*)d_in[1];
  const int* target = (const int*)d_in[2];
  float* out = (float*)d_out;
  char* ws = (char*)d_ws;

  __hip_bfloat16* wnb = (__hip_bfloat16*)ws;                     // 8 MB
  __hip_bfloat16* ebf = (__hip_bfloat16*)(ws + (size_t)(8u << 20));   // 32 MB
  float* Sf   = (float*)(ws + (size_t)(40u << 20));              // 16 KB
  float* part = (float*)(ws + (size_t)(40u << 20) + 16384);      // 64 KB

  k_norm<<<dim3(CDIM), dim3(256), 0, stream>>>(weight, wnb, Sf);
  k_simexp<<<dim3(32, 32), dim3(256), 0, stream>>>(wnb, ebf, Sf);
  k_loss<<<dim3(BDIM), dim3(256), 0, stream>>>(pred, target, ebf, Sf, part);
  k_final<<<dim3(1), dim3(256), 0, stream>>>(part, out);
}

// Round 3
// 129.256 us; speedup vs baseline: 1.2757x; 1.1250x over previous
//
#include <hip/hip_runtime.h>
#include <hip/hip_bf16.h>

#define CDIM 4096
#define DDIM 1024
#define BDIM 16384
#define EDIAG 2.7182818284590452f

using frag_ab = __attribute__((ext_vector_type(8))) short;   // 8 bf16 (4 VGPRs)
using frag_cd = __attribute__((ext_vector_type(4))) float;   // 4 fp32

typedef __attribute__((address_space(1))) const void gvoid;
typedef __attribute__((address_space(3))) void lvoid;

__device__ __forceinline__ float block_sum(float v, float* red) {
  int t = threadIdx.x;
  #pragma unroll
  for (int off = 32; off; off >>= 1) v += __shfl_xor(v, off);
  __syncthreads();
  if ((t & 63) == 0) red[t >> 6] = v;
  __syncthreads();
  return (red[0] + red[1]) + (red[2] + red[3]);
}

__device__ __forceinline__ float bf2f(short s) {
  return __uint_as_float(((unsigned)(unsigned short)s) << 16);
}

// ---- Kernel A: wn = bf16( weight_row / max(||row||, 1e-8) ); also zero Sf ----
__global__ __launch_bounds__(256) void k_norm(const float* __restrict__ w,
                                              __hip_bfloat16* __restrict__ wnb,
                                              float* __restrict__ Sf) {
  __shared__ float red[4];
  __shared__ float s_inv;
  int row = blockIdx.x, t = threadIdx.x;
  const float4* wr = (const float4*)(w + (size_t)row * DDIM);
  float4 x = wr[t];
  float ss = (x.x * x.x + x.y * x.y) + (x.z * x.z + x.w * x.w);
  ss = block_sum(ss, red);
  if (t == 0) {
    s_inv = 1.0f / fmaxf(sqrtf(ss), 1e-8f);
    Sf[row] = 0.0f;
  }
  __syncthreads();
  float inv = s_inv;
  __hip_bfloat16* o = wnb + (size_t)row * DDIM + t * 4;
  o[0] = __float2bfloat16(x.x * inv);
  o[1] = __float2bfloat16(x.y * inv);
  o[2] = __float2bfloat16(x.z * inv);
  o[3] = __float2bfloat16(x.w * inv);
}

// ---- Kernel B: e = bf16(exp(wn @ wn^T)), upper-triangle blocks only ----
// 128x128 tile, BK=64, 4 waves (2x2), XOR-swizzled LDS (pre-swizzled gload src),
// fused row-sum atomics; off-diagonal blocks mirror via LDS transpose + col sums.
__global__ __launch_bounds__(256) void k_simexp(const __hip_bfloat16* __restrict__ wb,
                                                __hip_bfloat16* __restrict__ ebf,
                                                float* __restrict__ Sf) {
  __shared__ char smem[32768];                 // A[128][64] | B[128][64] bf16; reused as T[128][128]
  int tid = threadIdx.x;
  int lane = tid & 63, wid = tid >> 6;
  int l15 = lane & 15, lk = (lane >> 4) * 8;
  int wm = wid >> 1, wn2 = wid & 1;

  // upper-triangle decode: pairs (brow<=bcol), idx = brow*(65-brow)/2 + (bcol-brow)
  int bi = blockIdx.x;
  int r = (int)((65.0f - sqrtf(4225.0f - 8.0f * (float)bi)) * 0.5f);
  if (r < 0) r = 0; if (r > 31) r = 31;
  while (r * (65 - r) / 2 > bi) --r;
  while ((r + 1) * (64 - r) / 2 <= bi) ++r;
  int brow = r;
  int bcol = r + (bi - r * (65 - r) / 2);
  bool diag = (brow == bcol);

  // staging: thread t covers rows srow=t/8 (stride 32 per round), 16B chunk t&7.
  // LDS dest is linear (tid*16); global SOURCE is pre-swizzled: chunk ^= (row&7).
  int srow = tid >> 3;
  int swzel = ((tid & 7) ^ (srow & 7)) * 8;    // element offset within row
  const __hip_bfloat16* gA = wb + (size_t)(brow * 128 + srow) * DDIM + swzel;
  const __hip_bfloat16* gB = wb + (size_t)(bcol * 128 + srow) * DDIM + swzel;
  char* lA = smem + tid * 16;
  char* lB = smem + 16384 + tid * 16;

  // frag read bases: row = w?*64 + l15 + m*16; (row&7)==(l15&7) since 16|m*16, 64|w*64
  int xorb = (l15 & 7) << 4;                   // byte xor for swizzled read
  const char* pa0 = smem + (wm * 64 + l15) * 128;
  const char* pb0 = smem + 16384 + (wn2 * 64 + l15) * 128;

  frag_cd acc[4][4] = {};

  for (int k0 = 0; k0 < DDIM; k0 += 64) {
    #pragma unroll
    for (int rr = 0; rr < 4; rr++) {
      __builtin_amdgcn_global_load_lds((gvoid*)(gA + k0 + (size_t)rr * 32 * DDIM),
                                       (lvoid*)(lA + rr * 4096), 16, 0, 0);
      __builtin_amdgcn_global_load_lds((gvoid*)(gB + k0 + (size_t)rr * 32 * DDIM),
                                       (lvoid*)(lB + rr * 4096), 16, 0, 0);
    }
    __syncthreads();
    #pragma unroll
    for (int ks = 0; ks < 2; ks++) {
      int off = (((ks * 32 + lk) * 2) ^ xorb);
      frag_ab a[4], b[4];
      #pragma unroll
      for (int m = 0; m < 4; m++) a[m] = *(const frag_ab*)(const void*)(pa0 + m * (16 * 128) + off);
      #pragma unroll
      for (int n = 0; n < 4; n++) b[n] = *(const frag_ab*)(const void*)(pb0 + n * (16 * 128) + off);
      #pragma unroll
      for (int m = 0; m < 4; m++)
        #pragma unroll
        for (int n = 0; n < 4; n++)
          acc[m][n] = __builtin_amdgcn_mfma_f32_16x16x32_bf16(a[m], b[n], acc[m][n], 0, 0, 0);
    }
    __syncthreads();
  }

  // exp in place
  #pragma unroll
  for (int m = 0; m < 4; m++)
    #pragma unroll
    for (int n = 0; n < 4; n++)
      #pragma unroll
      for (int j = 0; j < 4; j++)
        acc[m][n][j] = __expf(acc[m][n][j]);

  // C/D layout: col = lane&15, row = (lane>>4)*4 + reg
  int rg = (lane >> 4) * 4;
  int r0g = brow * 128 + wm * 64;
  int c0g = bcol * 128 + wn2 * 64 + l15;

  // normal tile store + row sums
  #pragma unroll
  for (int m = 0; m < 4; m++)
    #pragma unroll
    for (int j = 0; j < 4; j++) {
      int rglob = r0g + m * 16 + rg + j;
      float rsum = 0.f;
      #pragma unroll
      for (int n = 0; n < 4; n++) {
        float ex = acc[m][n][j];
        ebf[(size_t)rglob * CDIM + c0g + n * 16] = __float2bfloat16(ex);
        rsum += ex;
      }
      rsum += __shfl_xor(rsum, 1);
      rsum += __shfl_xor(rsum, 2);
      rsum += __shfl_xor(rsum, 4);
      rsum += __shfl_xor(rsum, 8);
      if (l15 == 0) atomicAdd(&Sf[rglob], rsum);
    }

  if (!diag) {
    // mirror tile: stage transposed into swizzled LDS (safe: all LDS reads done
    // before the K-loop's final barrier), then coalesced 16B row writes.
    #pragma unroll
    for (int m = 0; m < 4; m++)
      #pragma unroll
      for (int n = 0; n < 4; n++) {
        int cloc = wn2 * 64 + n * 16 + l15;
        int xc = (cloc & 7) << 4;
        #pragma unroll
        for (int j = 0; j < 4; j++) {
          int rloc = wm * 64 + m * 16 + rg + j;
          *(__hip_bfloat16*)(smem + cloc * 256 + ((rloc * 2) ^ xc)) =
              __float2bfloat16(acc[m][n][j]);
        }
        if (m == 0) {
          // column sums (over all 16 rows this lane holds, plus cross-rg)
          float cs = 0.f;
          #pragma unroll
          for (int mm = 0; mm < 4; mm++)
            #pragma unroll
            for (int j = 0; j < 4; j++) cs += acc[mm][n][j];
          cs += __shfl_xor(cs, 16);
          cs += __shfl_xor(cs, 32);
          if (lane < 16) atomicAdd(&Sf[bcol * 128 + wn2 * 64 + n * 16 + l15], cs);
        }
      }
    __syncthreads();
    #pragma unroll
    for (int it = 0; it < 8; it++) {
      int ct = it * 16 + (tid >> 4);           // original col = mirror row, 0..127
      int rch = (tid & 15) * 8;                // element offset within mirror row
      frag_ab v = *(const frag_ab*)(const void*)(smem + ct * 256 + ((rch * 2) ^ ((ct & 7) << 4)));
      *(frag_ab*)(void*)((char*)(ebf + (size_t)(bcol * 128 + ct) * CDIM + brow * 128 + rch)) = v;
    }
  }
}

// ---- Kernel C: per-sample loss ----
__global__ __launch_bounds__(256) void k_loss(const float* __restrict__ pred,
                                              const int* __restrict__ tgt,
                                              const __hip_bfloat16* __restrict__ ebf,
                                              const float* __restrict__ Sf,
                                              float* __restrict__ part) {
  __shared__ float red[4];
  int i = blockIdx.x, t = threadIdx.x;
  const float4* pr = (const float4*)(pred + (size_t)i * CDIM);
  float4 loc[4];
  float mx = -3.4e38f;
  #pragma unroll
  for (int j = 0; j < 4; j++) {
    float4 v = pr[t + j * 256];
    loc[j] = v;
    mx = fmaxf(fmaxf(mx, fmaxf(v.x, v.y)), fmaxf(v.z, v.w));
  }
  #pragma unroll
  for (int off = 32; off; off >>= 1) mx = fmaxf(mx, __shfl_xor(mx, off));
  if ((t & 63) == 0) red[t >> 6] = mx;
  __syncthreads();
  mx = fmaxf(fmaxf(red[0], red[1]), fmaxf(red[2], red[3]));

  float se = 0.f;
  #pragma unroll
  for (int j = 0; j < 4; j++)
    se += (__expf(loc[j].x - mx) + __expf(loc[j].y - mx)) +
          (__expf(loc[j].z - mx) + __expf(loc[j].w - mx));
  se = block_sum(se, red);
  float lse = mx + __logf(se);

  int tg = tgt[i];
  const short4* er = (const short4*)(ebf + (size_t)tg * CDIM);
  float dot = 0.f;
  #pragma unroll
  for (int j = 0; j < 4; j++) {
    short4 ev = er[t + j * 256];
    dot += (bf2f(ev.x) * loc[j].x + bf2f(ev.y) * loc[j].y) +
           (bf2f(ev.z) * loc[j].z + bf2f(ev.w) * loc[j].w);
  }
  dot = block_sum(dot, red);

  if (t == 0) {
    float pt = pred[(size_t)i * CDIM + tg];
    float ce = lse - pt;
    float S = Sf[tg];
    float t2 = (S * lse - dot - EDIAG * ce) / (S - EDIAG);
    part[i] = 0.9f * ce + 0.1f * t2;
  }
}

// ---- Kernel D: deterministic final reduce ----
__global__ __launch_bounds__(256) void k_final(const float* __restrict__ part,
                                               float* __restrict__ out) {
  __shared__ float red[4];
  int t = threadIdx.x;
  float s = 0.f;
  for (int i = t; i < BDIM; i += 256) s += part[i];
  s = block_sum(s, red);
  if (t == 0) out[0] = s * (1.0f / BDIM);
}

extern "C" void kernel_launch(void* const* d_in, const int* in_sizes, int n_in,
                              void* d_out, int out_size, void* d_ws, size_t ws_size,
                              hipStream_t stream) {
  const float* pred = (const float*)d_in[0];
  const float* weight = (const float*)d_in[1];
  const int* target = (const int*)d_in[2];
  float* out = (float*)d_out;
  char* ws = (char*)d_ws;

  __hip_bfloat16* wnb = (__hip_bfloat16*)ws;                          // 8 MB
  __hip_bfloat16* ebf = (__hip_bfloat16*)(ws + (size_t)(8u << 20));   // 32 MB
  float* Sf   = (float*)(ws + (size_t)(40u << 20));                   // 16 KB
  float* part = (float*)(ws + (size_t)(40u << 20) + 16384);           // 64 KB

  k_norm<<<dim3(CDIM), dim3(256), 0, stream>>>(weight, wnb, Sf);
  k_simexp<<<dim3(528), dim3(256), 0, stream>>>(wnb, ebf, Sf);
  k_loss<<<dim3(BDIM), dim3(256), 0, stream>>>(pred, target, ebf, Sf, part);
  k_final<<<dim3(1), dim3(256), 0, stream>>>(part, out);
}

// Round 4
// 128.004 us; speedup vs baseline: 1.2882x; 1.0098x over previous
//
#include <hip/hip_runtime.h>
#include <hip/hip_bf16.h>

#define CDIM 4096
#define DDIM 1024
#define BDIM 16384
#define EDIAG 2.7182818284590452f

using frag_ab = __attribute__((ext_vector_type(8))) short;   // 8 bf16 (4 VGPRs)
using frag_cd = __attribute__((ext_vector_type(4))) float;   // 4 fp32

typedef __attribute__((address_space(1))) const void gvoid;
typedef __attribute__((address_space(3))) void lvoid;

__device__ __forceinline__ float block_sum(float v, float* red) {
  int t = threadIdx.x;
  #pragma unroll
  for (int off = 32; off; off >>= 1) v += __shfl_xor(v, off);
  __syncthreads();
  if ((t & 63) == 0) red[t >> 6] = v;
  __syncthreads();
  return (red[0] + red[1]) + (red[2] + red[3]);
}

__device__ __forceinline__ float bf2f(short s) {
  return __uint_as_float(((unsigned)(unsigned short)s) << 16);
}

__device__ __forceinline__ unsigned short f2bfbits(float f) {
  __hip_bfloat16 b = __float2bfloat16(f);
  return *(unsigned short*)&b;
}

// ---- Kernel A: wn = bf16( weight_row / max(||row||, 1e-8) ); also zero Sf ----
__global__ __launch_bounds__(256) void k_norm(const float* __restrict__ w,
                                              __hip_bfloat16* __restrict__ wnb,
                                              float* __restrict__ Sf) {
  __shared__ float red[4];
  __shared__ float s_inv;
  int row = blockIdx.x, t = threadIdx.x;
  const float4* wr = (const float4*)(w + (size_t)row * DDIM);
  float4 x = wr[t];
  float ss = (x.x * x.x + x.y * x.y) + (x.z * x.z + x.w * x.w);
  ss = block_sum(ss, red);
  if (t == 0) {
    s_inv = 1.0f / fmaxf(sqrtf(ss), 1e-8f);
    Sf[row] = 0.0f;
  }
  __syncthreads();
  float inv = s_inv;
  ushort4 o;
  o.x = f2bfbits(x.x * inv);
  o.y = f2bfbits(x.y * inv);
  o.z = f2bfbits(x.z * inv);
  o.w = f2bfbits(x.w * inv);
  *(ushort4*)(wnb + (size_t)row * DDIM + t * 4) = o;
}

// ---- Kernel B: e = bf16(exp(wn @ wn^T)), upper-triangle blocks only ----
// 128x128 tile, BK=64, 8 waves (2Mx4N, each 64x32 out), double-buffered LDS,
// XOR-swizzled (pre-swizzled gload source + swizzled ds_read), fused row-sum
// atomics; off-diagonal blocks mirror via swizzled LDS transpose + col sums.
__global__ __launch_bounds__(512) void k_simexp(const __hip_bfloat16* __restrict__ wb,
                                                __hip_bfloat16* __restrict__ ebf,
                                                float* __restrict__ Sf) {
  __shared__ char smem[65536];                 // 2 bufs x (A[128][64]|B[128][64]) bf16
  int tid = threadIdx.x;
  int lane = tid & 63, wid = tid >> 6;
  int l15 = lane & 15, lk = (lane >> 4) * 8;
  int wm = wid >> 2, wn4 = wid & 3;            // 2x4 waves, each 64x32 output

  // upper-triangle decode: pairs (brow<=bcol), idx = brow*(65-brow)/2 + (bcol-brow)
  int bi = blockIdx.x;
  int r = (int)((65.0f - sqrtf(4225.0f - 8.0f * (float)bi)) * 0.5f);
  if (r < 0) r = 0; if (r > 31) r = 31;
  while (r * (65 - r) / 2 > bi) --r;
  while ((r + 1) * (64 - r) / 2 <= bi) ++r;
  int brow = r;
  int bcol = r + (bi - r * (65 - r) / 2);
  bool diag = (brow == bcol);

  // staging: thread t covers row srow=t/8 (64 rows per 8KB round), 16B chunk t&7.
  // LDS dest linear (tid*16); global SOURCE pre-swizzled: chunk ^= (row&7).
  int srow = tid >> 3;
  int swzel = ((tid & 7) ^ (srow & 7)) * 8;
  const __hip_bfloat16* gA0 = wb + (size_t)(brow * 128 + srow) * DDIM + swzel;
  const __hip_bfloat16* gA1 = gA0 + (size_t)64 * DDIM;
  const __hip_bfloat16* gB0 = wb + (size_t)(bcol * 128 + srow) * DDIM + swzel;
  const __hip_bfloat16* gB1 = gB0 + (size_t)64 * DDIM;
  int ldst = tid * 16;

#define STAGE(bufbase, k0)                                                                  \
  do {                                                                                      \
    __builtin_amdgcn_global_load_lds((gvoid*)(gA0 + (k0)), (lvoid*)(smem + (bufbase) + ldst),         16, 0, 0); \
    __builtin_amdgcn_global_load_lds((gvoid*)(gA1 + (k0)), (lvoid*)(smem + (bufbase) + 8192 + ldst),  16, 0, 0); \
    __builtin_amdgcn_global_load_lds((gvoid*)(gB0 + (k0)), (lvoid*)(smem + (bufbase) + 16384 + ldst), 16, 0, 0); \
    __builtin_amdgcn_global_load_lds((gvoid*)(gB1 + (k0)), (lvoid*)(smem + (bufbase) + 24576 + ldst), 16, 0, 0); \
  } while (0)

  int xorb = (l15 & 7) << 4;                   // byte xor for swizzled ds_read
  int aoff = (wm * 64 + l15) * 128;
  int boff = 16384 + (wn4 * 32 + l15) * 128;

  frag_cd acc[4][2] = {};

  STAGE(0, 0);
  __syncthreads();
  int cur = 0;
  for (int t = 0; t < 16; t++) {
    if (t < 15) STAGE((cur ^ 1) * 32768, (t + 1) * 64);
    const char* base = smem + cur * 32768;
    const char* pa0 = base + aoff;
    const char* pb0 = base + boff;
    #pragma unroll
    for (int ks = 0; ks < 2; ks++) {
      int off = ((ks * 32 + lk) * 2) ^ xorb;
      frag_ab a[4], b[2];
      #pragma unroll
      for (int m = 0; m < 4; m++) a[m] = *(const frag_ab*)(const void*)(pa0 + m * 2048 + off);
      #pragma unroll
      for (int n = 0; n < 2; n++) b[n] = *(const frag_ab*)(const void*)(pb0 + n * 2048 + off);
      #pragma unroll
      for (int m = 0; m < 4; m++)
        #pragma unroll
        for (int n = 0; n < 2; n++)
          acc[m][n] = __builtin_amdgcn_mfma_f32_16x16x32_bf16(a[m], b[n], acc[m][n], 0, 0, 0);
    }
    __syncthreads();
    cur ^= 1;
  }
#undef STAGE

  // exp in place
  #pragma unroll
  for (int m = 0; m < 4; m++)
    #pragma unroll
    for (int n = 0; n < 2; n++)
      #pragma unroll
      for (int j = 0; j < 4; j++)
        acc[m][n][j] = __expf(acc[m][n][j]);

  // C/D layout: col = lane&15, row = (lane>>4)*4 + reg
  int rg = (lane >> 4) * 4;
  int r0g = brow * 128 + wm * 64;
  int c0g = bcol * 128 + wn4 * 32 + l15;

  // normal tile store + row sums (each wave covers a 32-col segment)
  #pragma unroll
  for (int m = 0; m < 4; m++)
    #pragma unroll
    for (int j = 0; j < 4; j++) {
      int rglob = r0g + m * 16 + rg + j;
      float rsum = 0.f;
      #pragma unroll
      for (int n = 0; n < 2; n++) {
        float ex = acc[m][n][j];
        ebf[(size_t)rglob * CDIM + c0g + n * 16] = __float2bfloat16(ex);
        rsum += ex;
      }
      rsum += __shfl_xor(rsum, 1);
      rsum += __shfl_xor(rsum, 2);
      rsum += __shfl_xor(rsum, 4);
      rsum += __shfl_xor(rsum, 8);
      if (l15 == 0) atomicAdd(&Sf[rglob], rsum);
    }

  if (!diag) {
    // mirror tile: stage transposed into swizzled LDS (bufs dead now), then
    // coalesced 16B row writes; col sums feed the mirror rows' Sf.
    #pragma unroll
    for (int n = 0; n < 2; n++) {
      int cloc = wn4 * 32 + n * 16 + l15;
      int xc = (cloc & 7) << 4;
      #pragma unroll
      for (int m = 0; m < 4; m++)
        #pragma unroll
        for (int j = 0; j < 4; j++) {
          int rloc = wm * 64 + m * 16 + rg + j;
          *(__hip_bfloat16*)(smem + cloc * 256 + ((rloc * 2) ^ xc)) =
              __float2bfloat16(acc[m][n][j]);
        }
      float cs = 0.f;
      #pragma unroll
      for (int mm = 0; mm < 4; mm++)
        #pragma unroll
        for (int j = 0; j < 4; j++) cs += acc[mm][n][j];
      cs += __shfl_xor(cs, 16);
      cs += __shfl_xor(cs, 32);
      if (lane < 16) atomicAdd(&Sf[bcol * 128 + wn4 * 32 + n * 16 + l15], cs);
    }
    __syncthreads();
    #pragma unroll
    for (int it = 0; it < 4; it++) {
      int ct = it * 32 + (tid >> 4);           // mirror row (= original col), 0..127
      int rch = (tid & 15) * 8;                // element offset within mirror row
      frag_ab v = *(const frag_ab*)(const void*)(smem + ct * 256 + ((rch * 2) ^ ((ct & 7) << 4)));
      *(frag_ab*)(void*)((char*)(ebf + (size_t)(bcol * 128 + ct) * CDIM + brow * 128 + rch)) = v;
    }
  }
}

// ---- Kernel C: per-sample loss ----
__global__ __launch_bounds__(256) void k_loss(const float* __restrict__ pred,
                                              const int* __restrict__ tgt,
                                              const __hip_bfloat16* __restrict__ ebf,
                                              const float* __restrict__ Sf,
                                              float* __restrict__ part) {
  __shared__ float red[4];
  int i = blockIdx.x, t = threadIdx.x;
  const float4* pr = (const float4*)(pred + (size_t)i * CDIM);
  float4 loc[4];
  float mx = -3.4e38f;
  #pragma unroll
  for (int j = 0; j < 4; j++) {
    float4 v = pr[t + j * 256];
    loc[j] = v;
    mx = fmaxf(fmaxf(mx, fmaxf(v.x, v.y)), fmaxf(v.z, v.w));
  }
  #pragma unroll
  for (int off = 32; off; off >>= 1) mx = fmaxf(mx, __shfl_xor(mx, off));
  if ((t & 63) == 0) red[t >> 6] = mx;
  __syncthreads();
  mx = fmaxf(fmaxf(red[0], red[1]), fmaxf(red[2], red[3]));

  float se = 0.f;
  #pragma unroll
  for (int j = 0; j < 4; j++)
    se += (__expf(loc[j].x - mx) + __expf(loc[j].y - mx)) +
          (__expf(loc[j].z - mx) + __expf(loc[j].w - mx));
  se = block_sum(se, red);
  float lse = mx + __logf(se);

  int tg = tgt[i];
  const short4* er = (const short4*)(ebf + (size_t)tg * CDIM);
  float dot = 0.f;
  #pragma unroll
  for (int j = 0; j < 4; j++) {
    short4 ev = er[t + j * 256];
    dot += (bf2f(ev.x) * loc[j].x + bf2f(ev.y) * loc[j].y) +
           (bf2f(ev.z) * loc[j].z + bf2f(ev.w) * loc[j].w);
  }
  dot = block_sum(dot, red);

  if (t == 0) {
    float pt = pred[(size_t)i * CDIM + tg];
    float ce = lse - pt;
    float S = Sf[tg];
    float t2 = (S * lse - dot - EDIAG * ce) / (S - EDIAG);
    part[i] = 0.9f * ce + 0.1f * t2;
  }
}

// ---- Kernel D: deterministic final reduce ----
__global__ __launch_bounds__(256) void k_final(const float* __restrict__ part,
                                               float* __restrict__ out) {
  __shared__ float red[4];
  int t = threadIdx.x;
  float s = 0.f;
  for (int i = t; i < BDIM; i += 256) s += part[i];
  s = block_sum(s, red);
  if (t == 0) out[0] = s * (1.0f / BDIM);
}

extern "C" void kernel_launch(void* const* d_in, const int* in_sizes, int n_in,
                              void* d_out, int out_size, void* d_ws, size_t ws_size,
                              hipStream_t stream) {
  const float* pred = (const float*)d_in[0];
  const float* weight = (const float*)d_in[1];
  const int* target = (const int*)d_in[2];
  float* out = (float*)d_out;
  char* ws = (char*)d_ws;

  __hip_bfloat16* wnb = (__hip_bfloat16*)ws;                          // 8 MB
  __hip_bfloat16* ebf = (__hip_bfloat16*)(ws + (size_t)(8u << 20));   // 32 MB
  float* Sf   = (float*)(ws + (size_t)(40u << 20));                   // 16 KB
  float* part = (float*)(ws + (size_t)(40u << 20) + 16384);           // 64 KB

  k_norm<<<dim3(CDIM), dim3(256), 0, stream>>>(weight, wnb, Sf);
  k_simexp<<<dim3(528), dim3(512), 0, stream>>>(wnb, ebf, Sf);
  k_loss<<<dim3(BDIM), dim3(256), 0, stream>>>(pred, target, ebf, Sf, part);
  k_final<<<dim3(1), dim3(256), 0, stream>>>(part, out);
}